// Round 2
// baseline (1048.414 us; speedup 1.0000x reference)
//
#include <hip/hip_runtime.h>
#include <hip/hip_bf16.h>

#define CCH 128
#define HHH 128
#define WWW 128
#define HWX 16384           // H*W
#define NHD 4
#define HD  32
#define SCALE 0.17677669529663687f

typedef unsigned int  u32;
typedef unsigned short u16;
typedef short s16x8 __attribute__((ext_vector_type(8)));   // 8 bf16 (4 VGPRs)
typedef float f32x4 __attribute__((ext_vector_type(4)));   // MFMA C/D frag

__device__ __forceinline__ float bflo(u32 u) { return __uint_as_float(u << 16); }
__device__ __forceinline__ float bfhi(u32 u) { return __uint_as_float(u & 0xffff0000u); }
__device__ __forceinline__ u16 f2bf(float f) {
  u32 u = __float_as_uint(f);
  u += 0x7fffu + ((u >> 16) & 1u);
  return (u16)(u >> 16);
}
__device__ __forceinline__ u32 pk2(float a, float b) {
  return (u32)f2bf(a) | ((u32)f2bf(b) << 16);
}
__device__ __forceinline__ float dot8(const float* qf, uint4 kk) {
  return qf[0]*bflo(kk.x) + qf[1]*bfhi(kk.x) + qf[2]*bflo(kk.y) + qf[3]*bfhi(kk.y)
       + qf[4]*bflo(kk.z) + qf[5]*bfhi(kk.z) + qf[6]*bflo(kk.w) + qf[7]*bfhi(kk.w);
}
__device__ __forceinline__ void axpy8(float* o, float w, uint4 vv) {
  o[0] += w*bflo(vv.x); o[1] += w*bfhi(vv.x); o[2] += w*bflo(vv.y); o[3] += w*bfhi(vv.y);
  o[4] += w*bflo(vv.z); o[5] += w*bfhi(vv.z); o[6] += w*bflo(vv.w); o[7] += w*bfhi(vv.w);
}

// ---------------- weight swizzle into MFMA fragment layouts (bf16)
// wfq: B-frag layout for qkv GEMM. idx = ((nt*4+kk)*64+lane)*8+j
//      holds W[k = kk*32 + (lane>>4)*8 + j][oc = nt*16 + (lane&15)], nt 0..23
//      oc<128: qk_w[oc][k]*SCALE (q), oc<256: qk_w[oc][k] (k), else v_w[oc-128-128][k]
// wfp: A-frag layout for proj GEMM. idx = ((mt*4+kk)*64+lane)*8+j
//      holds proj_w[oc = mt*16 + (lane&15)][k = kk*32 + (lane>>4)*8 + j], mt 0..7
__global__ __launch_bounds__(256) void wtrans_kernel(
    const float* __restrict__ qk_w, const float* __restrict__ v_w,
    const float* __restrict__ proj_w, u16* __restrict__ wfq, u16* __restrict__ wfp) {
  int idx = blockIdx.x * 256 + threadIdx.x;          // 0..65535
  if (idx < 49152) {
    int j = idx & 7, l = (idx >> 3) & 63, kk = (idx >> 9) & 3, nt = idx >> 11;
    int k = kk * 32 + (l >> 4) * 8 + j;
    int oc = nt * 16 + (l & 15);
    float val;
    if (oc < 256) { val = qk_w[oc * 128 + k]; if (oc < 128) val *= SCALE; }
    else          { val = v_w[(oc - 256) * 128 + k]; }
    wfq[idx] = f2bf(val);
  } else {
    int r = idx - 49152;                             // 0..16383
    int j = r & 7, l = (r >> 3) & 63, kk = (r >> 9) & 3, mt = r >> 11;
    int oc = mt * 16 + (l & 15);
    int k = kk * 32 + (l >> 4) * 8 + j;
    wfp[r] = f2bf(proj_w[oc * 128 + k]);
  }
}

// ---------------- argmax over sims[pix][256] -> L[pix], first-index tie-break
__global__ __launch_bounds__(256) void argmax_kernel(
    const float* __restrict__ sims, int* __restrict__ L) {
  const int wave = threadIdx.x >> 6, lane = threadIdx.x & 63;
  const int pix = blockIdx.x * 4 + wave;
  const float4 s4 = *(const float4*)(sims + (size_t)pix * 256 + lane * 4);
  float bv = s4.x; int bi = lane * 4;
  if (s4.y > bv) { bv = s4.y; bi = lane * 4 + 1; }
  if (s4.z > bv) { bv = s4.z; bi = lane * 4 + 2; }
  if (s4.w > bv) { bv = s4.w; bi = lane * 4 + 3; }
  #pragma unroll
  for (int off = 32; off > 0; off >>= 1) {
    float ov = __shfl_down(bv, off);
    int   oi = __shfl_down(bi, off);
    if (ov > bv || (ov == bv && oi < bi)) { bv = ov; bi = oi; }
  }
  if (lane == 0) L[pix] = bi;
}

// ---------------- QKV GEMM (MFMA): x[b][c][hw] fp32 -> q/k/v bf16 [pix][128]
// block: 64 pixels x 384 oc. wave w handles ntiles w*6..w*6+5, all 4 mtiles.
__global__ __launch_bounds__(256) void qkv_kernel(
    const float* __restrict__ x, const u16* __restrict__ wfq,
    u16* __restrict__ qb, u16* __restrict__ kb, u16* __restrict__ vb) {
  __shared__ __align__(16) u16 xs[64 * 136];         // [pix][c], pad 136 shorts
  const int t = threadIdx.x;
  const int pg0 = blockIdx.x * 64;
  const int b = blockIdx.x >> 8;
  const int hw0 = pg0 & (HWX - 1);
  const float* xb = x + (size_t)b * (CCH * HWX) + hw0;
  u32* xsw = (u32*)xs;
  #pragma unroll
  for (int it = 0; it < 16; ++it) {
    int flat = t + it * 256;                         // 0..4095 = 64 c2 x 64 pix
    int pix = flat & 63, c2 = flat >> 6;
    float f0 = xb[(size_t)(2 * c2) * HWX + pix];
    float f1 = xb[(size_t)(2 * c2 + 1) * HWX + pix];
    xsw[pix * 68 + c2] = pk2(f0, f1);
  }
  __syncthreads();

  const int w = t >> 6, lane = t & 63;
  const int l15 = lane & 15, quad = lane >> 4;

  s16x8 af[4][4];                                    // [mtile][kstep]
  #pragma unroll
  for (int m = 0; m < 4; ++m)
    #pragma unroll
    for (int kk = 0; kk < 4; ++kk)
      af[m][kk] = *(const s16x8*)(xs + (m * 16 + l15) * 136 + kk * 32 + quad * 8);

  f32x4 acc[6][4];                                   // [ntile][mtile]
  #pragma unroll
  for (int nt = 0; nt < 6; ++nt)
    #pragma unroll
    for (int m = 0; m < 4; ++m) acc[nt][m] = (f32x4){0.f, 0.f, 0.f, 0.f};

  const u16* wl = wfq + lane * 8;
  #pragma unroll
  for (int nt = 0; nt < 6; ++nt) {
    const int ntg = w * 6 + nt;
    s16x8 bf[4];
    #pragma unroll
    for (int kk = 0; kk < 4; ++kk)
      bf[kk] = *(const s16x8*)(wl + (size_t)(ntg * 4 + kk) * 512);
    #pragma unroll
    for (int m = 0; m < 4; ++m)
      #pragma unroll
      for (int kk = 0; kk < 4; ++kk)
        acc[nt][m] = __builtin_amdgcn_mfma_f32_16x16x32_bf16(af[m][kk], bf[kk], acc[nt][m], 0, 0, 0);
  }

  // epilogue: D row = pix = m*16 + quad*4 + r, col = oc = ntg*16 + l15
  #pragma unroll
  for (int nt = 0; nt < 6; ++nt) {
    const int oc = (w * 6 + nt) * 16 + l15;
    u16* base; int off;
    if (oc < 128)      { base = qb; off = oc; }
    else if (oc < 256) { base = kb; off = oc - 128; }
    else               { base = vb; off = oc - 256; }
    #pragma unroll
    for (int m = 0; m < 4; ++m) {
      const int pr = pg0 + m * 16 + quad * 4;
      #pragma unroll
      for (int r = 0; r < 4; ++r)
        base[((size_t)(pr + r) << 7) + off] = f2bf(acc[nt][m][r]);
    }
  }
}

// ---------------- attention: block = 16x16 query tile, 1 head (q/k/v bf16)
#define TPAD 40
__global__ __launch_bounds__(256) void attn_kernel(
    const u16* __restrict__ qb, const u16* __restrict__ kb, const u16* __restrict__ vb,
    const int* __restrict__ L, u16* __restrict__ aob) {
  __shared__ __align__(16) u16 kt[484 * TPAD];
  __shared__ __align__(16) u16 vt[484 * TPAD];
  __shared__ int lt[484];
  const int t = threadIdx.x;
  const int bid = blockIdx.x;
  const int h = bid & 3, tj = (bid >> 2) & 7, ti = (bid >> 5) & 7, b = bid >> 8;
  const int i0 = ti * 16, j0 = tj * 16;
  const int r0 = max(0, i0 - 3), r1 = min(HHH - 1, i0 + 18);
  const int c0 = max(0, j0 - 3), c1 = min(WWW - 1, j0 + 18);
  const int nr = r1 - r0 + 1, nc = c1 - c0 + 1;
  const int npix = nr * nc;
  const size_t bbase = (size_t)b * HWX;

  #pragma unroll
  for (int it = 0; it < 8; ++it) {
    int fl = t + it * 256;
    int p = fl >> 2, dq = fl & 3;
    if (p < npix) {
      int rr = p / nc, cc2 = p - rr * nc;
      size_t g = ((bbase + (size_t)(r0 + rr) * WWW + (c0 + cc2)) << 7) + h * HD + dq * 8;
      *(uint4*)(kt + p * TPAD + dq * 8) = *(const uint4*)(kb + g);
      *(uint4*)(vt + p * TPAD + dq * 8) = *(const uint4*)(vb + g);
    }
  }
  for (int it = 0; it < 2; ++it) {
    int p = t + it * 256;
    if (p < npix) {
      int rr = p / nc, cc2 = p - rr * nc;
      lt[p] = L[bbase + (size_t)(r0 + rr) * WWW + (c0 + cc2)];
    }
  }
  __syncthreads();

  const int qi = i0 + (t >> 4), qj = j0 + (t & 15);
  const int slab = ((qi >> 3) << 4) | (qj >> 3);
  const int rs = min(max(qi - 3, 0), HHH - 7) - r0;
  const int cs = min(max(qj - 3, 0), WWW - 7) - c0;

  float qf[32];
  const u16* qp = qb + ((bbase + (size_t)qi * WWW + qj) << 7) + h * HD;
  #pragma unroll
  for (int u = 0; u < 4; ++u) {
    uint4 qq = *(const uint4*)(qp + u * 8);
    qf[u*8+0]=bflo(qq.x); qf[u*8+1]=bfhi(qq.x); qf[u*8+2]=bflo(qq.y); qf[u*8+3]=bfhi(qq.y);
    qf[u*8+4]=bflo(qq.z); qf[u*8+5]=bfhi(qq.z); qf[u*8+6]=bflo(qq.w); qf[u*8+7]=bfhi(qq.w);
  }

  float lg[49];
  unsigned long long pm = 0ull;
  #pragma unroll
  for (int di = 0; di < 7; ++di) {
    #pragma unroll
    for (int dj = 0; dj < 7; ++dj) {
      const int p = (rs + di) * nc + (cs + dj);
      const u16* kp = kt + p * TPAD;
      float s = 0.f;
      #pragma unroll
      for (int u = 0; u < 4; ++u) {
        uint4 kk = *(const uint4*)(kp + u * 8);
        s += dot8(qf + u * 8, kk);
      }
      const int ii = di * 7 + dj;
      lg[ii] = s;
      if (lt[p] == slab) pm |= (1ull << ii);
    }
  }

  float mx = lg[0];
  #pragma unroll
  for (int ii = 1; ii < 49; ++ii) mx = fmaxf(mx, lg[ii]);
  float sa = 0.f, smv = 0.f;
  #pragma unroll
  for (int ii = 0; ii < 49; ++ii) {
    float e = __expf(lg[ii] - mx);
    lg[ii] = e;
    sa += e;
    if ((pm >> ii) & 1ull) smv += e;
  }
  const float inv = 1.f / (smv + 1e-8f * sa);

  float of[32];
  #pragma unroll
  for (int d = 0; d < 32; ++d) of[d] = 0.f;
  #pragma unroll
  for (int di = 0; di < 7; ++di) {
    #pragma unroll
    for (int dj = 0; dj < 7; ++dj) {
      const int ii = di * 7 + dj;
      const float wgt = ((pm >> ii) & 1ull) ? lg[ii] * inv : 0.f;
      const u16* vp = vt + ((rs + di) * nc + (cs + dj)) * TPAD;
      #pragma unroll
      for (int u = 0; u < 4; ++u) {
        uint4 vv = *(const uint4*)(vp + u * 8);
        axpy8(of + u * 8, wgt, vv);
      }
    }
  }
  u16* op = aob + ((bbase + (size_t)qi * WWW + qj) << 7) + h * HD;
  #pragma unroll
  for (int u = 0; u < 4; ++u) {
    uint4 o4;
    o4.x = pk2(of[u*8+0], of[u*8+1]); o4.y = pk2(of[u*8+2], of[u*8+3]);
    o4.z = pk2(of[u*8+4], of[u*8+5]); o4.w = pk2(of[u*8+6], of[u*8+7]);
    *(uint4*)(op + u * 8) = o4;
  }
}

// ---------------- proj GEMM (MFMA): ao bf16 [pix][128] @ wfp -> out fp32 [b][oc][hw]
// A = proj_w (M=128 oc), B = ao pixels (N=64). wave w: mtiles {2w,2w+1}, ntiles 0..3
__global__ __launch_bounds__(256) void proj_kernel(
    const u16* __restrict__ aob, const u16* __restrict__ wfp, float* __restrict__ out) {
  __shared__ __align__(16) u16 as_[64 * 136];
  const int t = threadIdx.x;
  const int pg0 = blockIdx.x * 64;
  const int b = blockIdx.x >> 8;
  const int hw0 = pg0 & (HWX - 1);
  #pragma unroll
  for (int it = 0; it < 4; ++it) {
    int flat = t + it * 256;                         // 0..1023 = 64 pix x 16 k8
    int pix = flat >> 4, k8 = flat & 15;
    uint4 v = *(const uint4*)(aob + ((size_t)(pg0 + pix) << 7) + k8 * 8);
    *(uint4*)(as_ + pix * 136 + k8 * 8) = v;
  }
  __syncthreads();

  const int w = t >> 6, lane = t & 63;
  const int l15 = lane & 15, quad = lane >> 4;

  s16x8 aw[2][4];                                    // [mt][kstep] from wfp
  const u16* wl = wfp + lane * 8;
  #pragma unroll
  for (int mt = 0; mt < 2; ++mt)
    #pragma unroll
    for (int kk = 0; kk < 4; ++kk)
      aw[mt][kk] = *(const s16x8*)(wl + (size_t)((2 * w + mt) * 4 + kk) * 512);

  f32x4 acc[2][4];                                   // [mt][nt]
  #pragma unroll
  for (int mt = 0; mt < 2; ++mt)
    #pragma unroll
    for (int nt = 0; nt < 4; ++nt) acc[mt][nt] = (f32x4){0.f, 0.f, 0.f, 0.f};

  #pragma unroll
  for (int nt = 0; nt < 4; ++nt) {
    s16x8 bf[4];
    #pragma unroll
    for (int kk = 0; kk < 4; ++kk)
      bf[kk] = *(const s16x8*)(as_ + (nt * 16 + l15) * 136 + kk * 32 + quad * 8);
    #pragma unroll
    for (int mt = 0; mt < 2; ++mt)
      #pragma unroll
      for (int kk = 0; kk < 4; ++kk)
        acc[mt][nt] = __builtin_amdgcn_mfma_f32_16x16x32_bf16(aw[mt][kk], bf[kk], acc[mt][nt], 0, 0, 0);
  }

  // D: row = oc = (2w+mt)*16 + quad*4 + r, col = pix = nt*16 + l15
  float* ob = out + (size_t)b * (CCH * HWX) + hw0;
  #pragma unroll
  for (int mt = 0; mt < 2; ++mt) {
    const int oc0 = (2 * w + mt) * 16 + quad * 4;
    #pragma unroll
    for (int nt = 0; nt < 4; ++nt) {
      const int pix = nt * 16 + l15;
      #pragma unroll
      for (int r = 0; r < 4; ++r)
        ob[(size_t)(oc0 + r) * HWX + pix] = acc[mt][nt][r];
    }
  }
}

extern "C" void kernel_launch(void* const* d_in, const int* in_sizes, int n_in,
                              void* d_out, int out_size, void* d_ws, size_t ws_size,
                              hipStream_t stream) {
  const float* x      = (const float*)d_in[0];
  const float* sims   = (const float*)d_in[1];
  const float* qk_w   = (const float*)d_in[2];
  const float* v_w    = (const float*)d_in[3];
  const float* proj_w = (const float*)d_in[4];
  float* out = (float*)d_out;

  // ws: q 32MiB | k 32MiB | v 32MiB | ao 32MiB (all bf16 [pix][128]) | L | wfq | wfp
  u16* qb  = (u16*)d_ws;
  u16* kb  = qb + 16777216;
  u16* vb  = kb + 16777216;
  u16* aob = vb + 16777216;
  int* L   = (int*)(aob + 16777216);
  u16* wfq = (u16*)(L + 131072);
  u16* wfp = wfq + 49152;

  wtrans_kernel<<<256, 256, 0, stream>>>(qk_w, v_w, proj_w, wfq, wfp);
  argmax_kernel<<<32768, 256, 0, stream>>>(sims, L);
  qkv_kernel<<<2048, 256, 0, stream>>>(x, wfq, qb, kb, vb);
  attn_kernel<<<2048, 256, 0, stream>>>(qb, kb, vb, L, aob);
  proj_kernel<<<2048, 256, 0, stream>>>(aob, wfp, out);
}